// Round 6
// baseline (164.627 us; speedup 1.0000x reference)
//
#include <hip/hip_runtime.h>
#include <math.h>

#define GRID 28
#define NP 784

// ======== INSTRUMENTATION: in-kernel body repeats (idempotent) ========
// k1 x6, k2 x8, k3 x12 — per-kernel cost = rocprof dur / multiplier.
#define K1_REP 6
#define K2_REP 8
#define K3_REP 12

// ---------- compile-time shell-sorted pair table ----------
struct PairTab { unsigned int pk[NP]; float d2[NP]; };
constexpr PairTab make_pairs() {
    PairTab t{};
    int cnt[1459] = {};
    for (int di = 0; di < GRID; ++di)
        for (int dj = 0; dj < GRID; ++dj) cnt[di*di + dj*dj]++;
    int off[1459] = {};
    int acc = 0;
    for (int s = 0; s < 1459; ++s) { off[s] = acc; acc += cnt[s]; }
    const double BY2 = (1.0/13.5) * (1.0/13.5);
    for (int di = 0; di < GRID; ++di)
        for (int dj = 0; dj < GRID; ++dj) {
            int s = di*di + dj*dj;
            int o = off[s]++;
            t.pk[o] = (unsigned)((di << 8) | dj);
            t.d2[o] = (float)((double)s * BY2);
        }
    return t;
}
__constant__ PairTab d_PT = make_pairs();

// ---------- conv band path: 4 output rows per block, register-rolling ----------
#define CB_SMEM 7328
__device__ void conv_band(const float* __restrict__ in,
                          const float* __restrict__ kA, const float* __restrict__ cbA,
                          const float* __restrict__ kB, const float* __restrict__ cbB,
                          float* __restrict__ outImg, int r0, float* smem)
{
    float* inl = smem;            // 240
    float* kAl = inl + 240;       // 288
    float* kBl = kAl + 288;       // 288
    float* cbl = kBl + 288;       // 32
    float* h   = cbl + 32;        // 6480
    const int tid = threadIdx.x;
    const float cbB0 = cbB[0];

    if (tid < 288)      { kAl[tid] = kA[tid]; kBl[tid] = kB[tid]; }
    else if (tid < 320) cbl[tid - 288] = cbA[tid - 288];
    else if (tid < 560) {
        const int i = tid - 320;
        const int lr = i / 30, col = i % 30;
        const int y = r0 - 2 + lr, ix = col - 1;
        inl[i] = ((unsigned)y < GRID && (unsigned)ix < GRID) ? in[y*GRID + ix] : 0.f;
    }
    {
        float4* h4 = (float4*)h;
        for (int i = tid; i < 6480/4; i += 1024) h4[i] = make_float4(0.f,0.f,0.f,0.f);
    }
    __syncthreads();

    if (tid < 896) {
        const int c = tid & 31, xx = tid >> 5;
        float ka0 = kAl[0*32+c], ka1 = kAl[1*32+c], ka2 = kAl[2*32+c];
        float ka3 = kAl[3*32+c], ka4 = kAl[4*32+c], ka5 = kAl[5*32+c];
        float ka6 = kAl[6*32+c], ka7 = kAl[7*32+c], ka8 = kAl[8*32+c];
        const float bias = cbl[c];
        float w00 = inl[0*30+xx], w01 = inl[0*30+xx+1], w02 = inl[0*30+xx+2];
        float w10 = inl[1*30+xx], w11 = inl[1*30+xx+1], w12 = inl[1*30+xx+2];
        float w20 = inl[2*30+xx], w21 = inl[2*30+xx+1], w22 = inl[2*30+xx+2];
        #pragma unroll
        for (int s = 0; s < 6; ++s) {
            const int y = r0 - 1 + s;
            float a = bias;
            a = fmaf(w00, ka0, a); a = fmaf(w01, ka1, a); a = fmaf(w02, ka2, a);
            a = fmaf(w10, ka3, a); a = fmaf(w11, ka4, a); a = fmaf(w12, ka5, a);
            a = fmaf(w20, ka6, a); a = fmaf(w21, ka7, a); a = fmaf(w22, ka8, a);
            if ((unsigned)y < GRID) h[(s*30 + xx + 1)*36 + c] = fmaxf(a, 0.f);
            if (s < 5) {
                w00 = w10; w01 = w11; w02 = w12;
                w10 = w20; w11 = w21; w12 = w22;
                w20 = inl[(s+3)*30+xx]; w21 = inl[(s+3)*30+xx+1]; w22 = inl[(s+3)*30+xx+2];
            }
        }
    }
    __syncthreads();

    if (tid < 448) {
        const int part = tid & 3, o = tid >> 2;
        const int xx = o % 28, ly = o / 28;
        const int y = r0 + ly;
        float a = 0.f;
        #pragma unroll
        for (int dy = 0; dy < 3; ++dy) {
            #pragma unroll
            for (int dx = 0; dx < 3; ++dx) {
                const float4* hb = (const float4*)&h[((ly+dy)*30 + xx+dx)*36 + part*8];
                const float4* kb = (const float4*)&kBl[(dy*3+dx)*32 + part*8];
                const float4 h0 = hb[0], h1 = hb[1];
                const float4 k0 = kb[0], k1 = kb[1];
                a += h0.x*k0.x; a += h0.y*k0.y; a += h0.z*k0.z; a += h0.w*k0.w;
                a += h1.x*k1.x; a += h1.y*k1.y; a += h1.z*k1.z; a += h1.w*k1.w;
            }
        }
        a += __shfl_xor(a, 1, 64);
        a += __shfl_xor(a, 2, 64);
        if (part == 0) outImg[y*GRID + xx] = fmaxf(a + cbB0, 0.f);
    }
}

// ---------- K1: conv1 (112 blocks) + dtm (784 blocks), body x K1_REP ----------
__global__ __launch_bounds__(1024, 8) void k1_kernel(const float* __restrict__ x,
        const float* __restrict__ k11, const float* __restrict__ cb11,
        const float* __restrict__ k12, const float* __restrict__ cb12,
        float* __restrict__ ws)
{
    __shared__ float smem[CB_SMEM];
    const int blk = blockIdx.x;
    const int tid = threadIdx.x;

    if (blk < 112) {                      // conv1: x -> x1o
        const int img = blk / 7, band = blk % 7;
        for (int rep = 0; rep < K1_REP; ++rep) {
            conv_band(x + img*NP, k11, cb11, k12, cb12, ws + 25088 + img*NP, band*4, smem);
            __syncthreads();
        }
        return;
    }

    // ---- dtm ----
    float* wimg = smem;
    float* red  = smem + 784;
    float* out1 = ws;
    float* out2 = ws + 12544;
    const int dblk = blk - 112;
    const int img = dblk / 49, grp = dblk % 49;
    const int w = tid >> 6, lane = tid & 63;
    const int pix = grp*16 + w;
    const int pr = pix / GRID, pc = pix % GRID;

    for (int rep = 0; rep < K1_REP; ++rep) {
        float v = 0.f;
        if (tid < NP) { v = x[img*NP + tid]; wimg[tid] = v; }
        for (int off = 32; off; off >>= 1) v += __shfl_down(v, off, 64);
        if (lane == 0) red[w] = v;
        __syncthreads();
        float sumw = 0.f;
        #pragma unroll
        for (int i = 0; i < 16; ++i) sumw += red[i];

        const float m0W1 = 0.05f * sumw;
        const float m0W2 = 0.2f  * sumw;
        float a1 = 0.f, a2 = 0.f, carry = 0.f;

        for (int k0 = 0; k0 < NP; k0 += 64) {
            const int idx = k0 + lane;
            const int ii  = idx < NP ? idx : NP-1;
            const unsigned p = d_PT.pk[ii];
            const float dd   = d_PT.d2[ii];
            const int di = (int)(p >> 8);
            const int dj = (int)(p & 255u);
            const int dG = di * GRID;
            const bool rpOK = (pr + di) < GRID;
            const bool rmOK = pr >= di;
            const bool cpOK = (pc + dj) < GRID;
            const bool cmOK = pc >= dj;
            float Wg = 0.f;
            if (rpOK && cpOK)               Wg += wimg[pix + dG + dj];
            if (dj && rpOK && cmOK)         Wg += wimg[pix + dG - dj];
            if (di && rmOK && cpOK)         Wg += wimg[pix - dG + dj];
            if (di && dj && rmOK && cmOK)   Wg += wimg[pix - dG - dj];
            if (idx >= NP) Wg = 0.f;
            float incl = Wg;
            #pragma unroll
            for (int d = 1; d < 64; d <<= 1) {
                const float t = __shfl_up(incl, d, 64);
                if (lane >= d) incl += t;
            }
            const float cumb = carry + (incl - Wg);
            const float e1 = fminf(fmaxf(m0W1 - cumb, 0.f), Wg);
            const float e2 = fminf(fmaxf(m0W2 - cumb, 0.f), Wg);
            a1 = fmaf(e1, dd, a1);
            a2 = fmaf(e2, dd, a2);
            carry += __shfl(incl, 63, 64);
            if (carry >= m0W2) break;
        }
        for (int m = 32; m; m >>= 1) { a1 += __shfl_xor(a1, m, 64); a2 += __shfl_xor(a2, m, 64); }
        if (lane == 0) {
            out1[img*NP + pix] = sqrtf(a1 / m0W1);
            out2[img*NP + pix] = sqrtf(a2 / m0W2);
        }
        __syncthreads();
    }
}

// ---------- K2: conv3 + conv4 band paths (224 blocks), body x K2_REP ----------
__global__ __launch_bounds__(1024, 8) void k2_kernel(
        const float* __restrict__ k31, const float* __restrict__ cb31,
        const float* __restrict__ k32, const float* __restrict__ cb32,
        const float* __restrict__ k41, const float* __restrict__ cb41,
        const float* __restrict__ k42, const float* __restrict__ cb42,
        float* __restrict__ ws)
{
    __shared__ float smem[CB_SMEM];
    const int blk = blockIdx.x;
    const float* x2_1 = ws;
    const float* x2_2 = ws + 12544;
    float* x3c = ws + 37632;
    float* x4c = ws + 50176;

    if (blk < 112) {
        const int img = blk / 7, band = blk % 7;
        for (int rep = 0; rep < K2_REP; ++rep) {
            conv_band(x2_1 + img*NP, k31, cb31, k32, cb32, x3c + img*NP, band*4, smem);
            __syncthreads();
        }
    } else {
        const int c = blk - 112;
        const int img = c / 7, band = c % 7;
        for (int rep = 0; rep < K2_REP; ++rep) {
            conv_band(x2_2 + img*NP, k41, cb41, k42, cb42, x4c + img*NP, band*4, smem);
            __syncthreads();
        }
    }
}

__device__ __forceinline__ float tseqA(int i) {
    if (i == 24) return 0.3f;
    return (float)((double)i * ((0.3 - 0.06)/24.0) + 0.06);
}
__device__ __forceinline__ float tseqB(int i) {
    if (i == 26) return 0.4f;
    return (float)((double)i * ((0.4 - 0.14)/26.0) + 0.14);
}

__device__ __forceinline__ void merge3(float& m0, float& m1, float& m2,
                                       float b0, float b1, float b2) {
    float r0, r1, r2;
    if (m0 <= b0) {
        r0 = m0;
        if (m1 <= b0) { r1 = m1; r2 = fminf(m2, b0); }
        else          { r1 = b0; r2 = fminf(m1, b1); }
    } else {
        r0 = b0;
        if (b1 <= m0) { r1 = b1; r2 = fminf(b2, m0); }
        else          { r1 = m0; r2 = fminf(m1, b1); }
    }
    m0 = r0; m1 = r1; m2 = r2;
}

__device__ __forceinline__ void ins3(float& m0, float& m1, float& m2, float v) {
    if (v < m0)      { m2 = m1; m1 = m0; m0 = v; }
    else if (v < m1) { m2 = m1; m1 = v; }
    else if (v < m2) { m2 = v; }
}

// ---------- K3: topo features + final MLP, body x K3_REP ----------
__global__ __launch_bounds__(1024) void tail_kernel(
        const float* __restrict__ W33, const float* __restrict__ b33,
        const float* __restrict__ W43, const float* __restrict__ b43,
        const float* __restrict__ W5,  const float* __restrict__ b5,
        const float* __restrict__ W6,  const float* __restrict__ b6,
        const float* __restrict__ W7,  const float* __restrict__ b7,
        const float* __restrict__ W8,  const float* __restrict__ b8,
        const float* __restrict__ ws,  float* __restrict__ out)
{
    __shared__ float xc[848];
    __shared__ float Wsm[4192];
    __shared__ float part[1024];
    __shared__ float h7[64];
    __shared__ float fsh[64];
    const int b = blockIdx.x, tid = threadIdx.x;
    const int w = tid >> 6, lane = tid & 63;
    const float* x2_1 = ws;
    const float* x2_2 = ws + 12544;
    const float* x1o  = ws + 25088;
    const float* x3c  = ws + 37632;
    const float* x4c  = ws + 50176;

    for (int rep = 0; rep < K3_REP; ++rep) {
        if (tid < NP) xc[tid] = x1o[b*NP + tid];

        for (int i = tid; i < 4192; i += 1024) {
            float v;
            if (i < 800)       v = W33[i];
            else if (i < 2096) v = W43[i - 800];
            else if (i < 2896) v = W5[i - 2096];
            else               v = W6[i - 2896];
            Wsm[i] = v;
        }

        // min3: 16 waves = 4 arrays x 4 segments of 196
        {
            const int arr = w >> 2, seg = w & 3;
            const float* src = (arr == 0) ? x3c : (arr == 1) ? x4c : (arr == 2) ? x2_1 : x2_2;
            src += b*NP + seg*196;
            const float v0 = src[lane];
            const float v1 = src[lane + 64];
            const float v2 = src[lane + 128];
            const float v3 = (lane < 4) ? src[lane + 192] : INFINITY;
            float m0 = INFINITY, m1 = INFINITY, m2 = INFINITY;
            ins3(m0, m1, m2, v0);
            ins3(m0, m1, m2, v1);
            ins3(m0, m1, m2, v2);
            ins3(m0, m1, m2, v3);
            for (int mask = 1; mask <= 32; mask <<= 1) {
                const float b0 = __shfl_xor(m0, mask, 64);
                const float b1 = __shfl_xor(m1, mask, 64);
                const float b2 = __shfl_xor(m2, mask, 64);
                merge3(m0, m1, m2, b0, b1, b2);
            }
            if (lane == 0) { fsh[w*3+0] = m0; fsh[w*3+1] = m1; fsh[w*3+2] = m2; }
        }
        __syncthreads();
        if (tid < 4) {
            float m0 = fsh[(tid*4+0)*3+0], m1 = fsh[(tid*4+0)*3+1], m2 = fsh[(tid*4+0)*3+2];
            #pragma unroll
            for (int s = 1; s < 4; ++s)
                merge3(m0, m1, m2, fsh[(tid*4+s)*3+0], fsh[(tid*4+s)*3+1], fsh[(tid*4+s)*3+2]);
            fsh[48 + tid*3 + 0] = m0; fsh[48 + tid*3 + 1] = m1; fsh[48 + tid*3 + 2] = m2;
        }
        __syncthreads();

        if (w < 4) {
            const int g = lane >> 4, j = lane & 15;
            const float f0 = fsh[48 + w*3 + 0], f1 = fsh[48 + w*3 + 1], f2 = fsh[48 + w*3 + 2];
            float acc = 0.f;
            if (w == 0 || w == 2) {
                const float* Wm = (w == 0) ? &Wsm[0] : &Wsm[2096];
                for (int i = g; i < 50; i += 4) {
                    const int t = i >> 1, k = i & 1;
                    const float ts = tseqA(t);
                    const float fk = k ? f1 : f0;
                    const float lam = fmaxf(fminf(ts - fk, 0.3f - ts), 0.f);
                    acc = fmaf(lam, Wm[i*16 + j], acc);
                }
            } else {
                const float* Wm = (w == 1) ? &Wsm[800] : &Wsm[2896];
                for (int i = g; i < 81; i += 4) {
                    const int t = i / 3, k = i - t*3;
                    const float ts = tseqB(t);
                    const float fk = (k == 0) ? f0 : (k == 1 ? f1 : f2);
                    const float lam = fmaxf(fminf(ts - fk, 0.4f - ts), 0.f);
                    acc = fmaf(lam, Wm[i*16 + j], acc);
                }
            }
            acc += __shfl_xor(acc, 16, 64);
            acc += __shfl_xor(acc, 32, 64);
            if (lane < 16) {
                const float* bv = (w == 0) ? b33 : (w == 1) ? b43 : (w == 2) ? b5 : b6;
                xc[784 + w*16 + lane] = fmaxf(acc + bv[lane], 0.f);
            }
        }
        __syncthreads();

        {
            float acc = 0.f;
            const int i0 = w * 53;
            const float* Wp = W7 + i0*64 + lane;
            #pragma unroll
            for (int r = 0; r < 53; ++r)
                acc = fmaf(xc[i0 + r], Wp[r*64], acc);
            part[w*64 + lane] = acc;
        }
        __syncthreads();
        if (tid < 64) {
            float s = b7[tid];
            #pragma unroll
            for (int k = 0; k < 16; ++k) s += part[k*64 + tid];
            h7[tid] = fmaxf(s, 0.f);
        }
        __syncthreads();

        if (w < 10) {
            float a2 = h7[lane] * W8[lane*10 + w];
            for (int m = 32; m; m >>= 1) a2 += __shfl_down(a2, m, 64);
            if (lane == 0) out[b*10 + w] = a2 + b8[w];
        }
        __syncthreads();
    }
}

extern "C" void kernel_launch(void* const* d_in, const int* in_sizes, int n_in,
                              void* d_out, int out_size, void* d_ws, size_t ws_size,
                              hipStream_t stream)
{
    const float* x    = (const float*)d_in[0];
    const float* k11  = (const float*)d_in[1];
    const float* cb11 = (const float*)d_in[2];
    const float* k12  = (const float*)d_in[3];
    const float* cb12 = (const float*)d_in[4];
    const float* k31  = (const float*)d_in[5];
    const float* cb31 = (const float*)d_in[6];
    const float* k32  = (const float*)d_in[7];
    const float* cb32 = (const float*)d_in[8];
    const float* k41  = (const float*)d_in[9];
    const float* cb41 = (const float*)d_in[10];
    const float* k42  = (const float*)d_in[11];
    const float* cb42 = (const float*)d_in[12];
    const float* W33  = (const float*)d_in[13];
    const float* b33  = (const float*)d_in[14];
    const float* W43  = (const float*)d_in[15];
    const float* b43  = (const float*)d_in[16];
    const float* W5   = (const float*)d_in[17];
    const float* b5   = (const float*)d_in[18];
    const float* W6   = (const float*)d_in[19];
    const float* b6   = (const float*)d_in[20];
    const float* W7   = (const float*)d_in[21];
    const float* b7   = (const float*)d_in[22];
    const float* W8   = (const float*)d_in[23];
    const float* b8   = (const float*)d_in[24];
    float* ws  = (float*)d_ws;
    float* out = (float*)d_out;

    k1_kernel  <<<dim3(896), dim3(1024), 0, stream>>>(x, k11, cb11, k12, cb12, ws);
    k2_kernel  <<<dim3(224), dim3(1024), 0, stream>>>(k31, cb31, k32, cb32,
                                                      k41, cb41, k42, cb42, ws);
    tail_kernel<<<dim3(16),  dim3(1024), 0, stream>>>(W33, b33, W43, b43, W5, b5, W6, b6,
                                                      W7, b7, W8, b8, ws, out);
}

// Round 8
// 57.992 us; speedup vs baseline: 2.8388x; 2.8388x over previous
//
#include <hip/hip_runtime.h>
#include <math.h>

#define GRID 28
#define NP 784

// ---------- compile-time shell-sorted pair table ----------
struct PairTab { unsigned int pk[NP]; float d2[NP]; };
constexpr PairTab make_pairs() {
    PairTab t{};
    int cnt[1459] = {};
    for (int di = 0; di < GRID; ++di)
        for (int dj = 0; dj < GRID; ++dj) cnt[di*di + dj*dj]++;
    int off[1459] = {};
    int acc = 0;
    for (int s = 0; s < 1459; ++s) { off[s] = acc; acc += cnt[s]; }
    const double BY2 = (1.0/13.5) * (1.0/13.5);
    for (int di = 0; di < GRID; ++di)
        for (int dj = 0; dj < GRID; ++dj) {
            int s = di*di + dj*dj;
            int o = off[s]++;
            t.pk[o] = (unsigned)((di << 8) | dj);
            t.d2[o] = (float)((double)s * BY2);
        }
    return t;
}
__constant__ PairTab d_PT = make_pairs();

// ---------- conv band path (K1 conv1 only): 4 output rows per block ----------
#define CB_SMEM 7328
__device__ void conv_band(const float* __restrict__ in,
                          const float* __restrict__ kA, const float* __restrict__ cbA,
                          const float* __restrict__ kB, const float* __restrict__ cbB,
                          float* __restrict__ outImg, int r0, float* smem)
{
    float* inl = smem;            // 240
    float* kAl = inl + 240;       // 288
    float* kBl = kAl + 288;       // 288
    float* cbl = kBl + 288;       // 32
    float* h   = cbl + 32;        // 6480
    const int tid = threadIdx.x;
    const float cbB0 = cbB[0];

    if (tid < 288)      { kAl[tid] = kA[tid]; kBl[tid] = kB[tid]; }
    else if (tid < 320) cbl[tid - 288] = cbA[tid - 288];
    else if (tid < 560) {
        const int i = tid - 320;
        const int lr = i / 30, col = i % 30;
        const int y = r0 - 2 + lr, ix = col - 1;
        inl[i] = ((unsigned)y < GRID && (unsigned)ix < GRID) ? in[y*GRID + ix] : 0.f;
    }
    {
        float4* h4 = (float4*)h;
        for (int i = tid; i < 6480/4; i += 1024) h4[i] = make_float4(0.f,0.f,0.f,0.f);
    }
    __syncthreads();

    if (tid < 896) {
        const int c = tid & 31, xx = tid >> 5;
        float ka0 = kAl[0*32+c], ka1 = kAl[1*32+c], ka2 = kAl[2*32+c];
        float ka3 = kAl[3*32+c], ka4 = kAl[4*32+c], ka5 = kAl[5*32+c];
        float ka6 = kAl[6*32+c], ka7 = kAl[7*32+c], ka8 = kAl[8*32+c];
        const float bias = cbl[c];
        float w00 = inl[0*30+xx], w01 = inl[0*30+xx+1], w02 = inl[0*30+xx+2];
        float w10 = inl[1*30+xx], w11 = inl[1*30+xx+1], w12 = inl[1*30+xx+2];
        float w20 = inl[2*30+xx], w21 = inl[2*30+xx+1], w22 = inl[2*30+xx+2];
        #pragma unroll
        for (int s = 0; s < 6; ++s) {
            const int y = r0 - 1 + s;
            float a = bias;
            a = fmaf(w00, ka0, a); a = fmaf(w01, ka1, a); a = fmaf(w02, ka2, a);
            a = fmaf(w10, ka3, a); a = fmaf(w11, ka4, a); a = fmaf(w12, ka5, a);
            a = fmaf(w20, ka6, a); a = fmaf(w21, ka7, a); a = fmaf(w22, ka8, a);
            if ((unsigned)y < GRID) h[(s*30 + xx + 1)*36 + c] = fmaxf(a, 0.f);
            if (s < 5) {
                w00 = w10; w01 = w11; w02 = w12;
                w10 = w20; w11 = w21; w12 = w22;
                w20 = inl[(s+3)*30+xx]; w21 = inl[(s+3)*30+xx+1]; w22 = inl[(s+3)*30+xx+2];
            }
        }
    }
    __syncthreads();

    if (tid < 448) {
        const int part = tid & 3, o = tid >> 2;
        const int xx = o % 28, ly = o / 28;
        const int y = r0 + ly;
        float a = 0.f;
        #pragma unroll
        for (int dy = 0; dy < 3; ++dy) {
            #pragma unroll
            for (int dx = 0; dx < 3; ++dx) {
                const float4* hb = (const float4*)&h[((ly+dy)*30 + xx+dx)*36 + part*8];
                const float4* kb = (const float4*)&kBl[(dy*3+dx)*32 + part*8];
                const float4 h0 = hb[0], h1 = hb[1];
                const float4 k0 = kb[0], k1 = kb[1];
                a += h0.x*k0.x; a += h0.y*k0.y; a += h0.z*k0.z; a += h0.w*k0.w;
                a += h1.x*k1.x; a += h1.y*k1.y; a += h1.z*k1.z; a += h1.w*k1.w;
            }
        }
        a += __shfl_xor(a, 1, 64);
        a += __shfl_xor(a, 2, 64);
        if (part == 0) outImg[y*GRID + xx] = fmaxf(a + cbB0, 0.f);
    }
}

// ---------- K1: conv1 (112 blocks) + dtm (784 blocks) — unchanged ----------
__global__ __launch_bounds__(1024, 8) void k1_kernel(const float* __restrict__ x,
        const float* __restrict__ k11, const float* __restrict__ cb11,
        const float* __restrict__ k12, const float* __restrict__ cb12,
        float* __restrict__ ws)
{
    __shared__ float smem[CB_SMEM];
    const int blk = blockIdx.x;
    const int tid = threadIdx.x;

    if (blk < 112) {                      // conv1: x -> x1o
        const int img = blk / 7, band = blk % 7;
        conv_band(x + img*NP, k11, cb11, k12, cb12, ws + 25088 + img*NP, band*4, smem);
        return;
    }

    // ---- dtm ----
    float* wimg = smem;
    float* red  = smem + 784;
    float* out1 = ws;
    float* out2 = ws + 12544;
    const int dblk = blk - 112;
    const int img = dblk / 49, grp = dblk % 49;
    const int w = tid >> 6, lane = tid & 63;

    float v = 0.f;
    if (tid < NP) { v = x[img*NP + tid]; wimg[tid] = v; }
    for (int off = 32; off; off >>= 1) v += __shfl_down(v, off, 64);
    if (lane == 0) red[w] = v;
    __syncthreads();
    float sumw = 0.f;
    #pragma unroll
    for (int i = 0; i < 16; ++i) sumw += red[i];

    const int pix = grp*16 + w;
    const int pr = pix / GRID, pc = pix % GRID;
    const float m0W1 = 0.05f * sumw;
    const float m0W2 = 0.2f  * sumw;
    float a1 = 0.f, a2 = 0.f, carry = 0.f;

    for (int k0 = 0; k0 < NP; k0 += 64) {
        const int idx = k0 + lane;
        const int ii  = idx < NP ? idx : NP-1;
        const unsigned p = d_PT.pk[ii];
        const float dd   = d_PT.d2[ii];
        const int di = (int)(p >> 8);
        const int dj = (int)(p & 255u);
        const int dG = di * GRID;
        const bool rpOK = (pr + di) < GRID;
        const bool rmOK = pr >= di;
        const bool cpOK = (pc + dj) < GRID;
        const bool cmOK = pc >= dj;
        float Wg = 0.f;
        if (rpOK && cpOK)               Wg += wimg[pix + dG + dj];
        if (dj && rpOK && cmOK)         Wg += wimg[pix + dG - dj];
        if (di && rmOK && cpOK)         Wg += wimg[pix - dG + dj];
        if (di && dj && rmOK && cmOK)   Wg += wimg[pix - dG - dj];
        if (idx >= NP) Wg = 0.f;
        float incl = Wg;
        #pragma unroll
        for (int d = 1; d < 64; d <<= 1) {
            const float t = __shfl_up(incl, d, 64);
            if (lane >= d) incl += t;
        }
        const float cumb = carry + (incl - Wg);
        const float e1 = fminf(fmaxf(m0W1 - cumb, 0.f), Wg);
        const float e2 = fminf(fmaxf(m0W2 - cumb, 0.f), Wg);
        a1 = fmaf(e1, dd, a1);
        a2 = fmaf(e2, dd, a2);
        carry += __shfl(incl, 63, 64);
        if (carry >= m0W2) break;
    }
    for (int m = 32; m; m >>= 1) { a1 += __shfl_xor(a1, m, 64); a2 += __shfl_xor(a2, m, 64); }
    if (lane == 0) {
        out1[img*NP + pix] = sqrtf(a1 / m0W1);
        out2[img*NP + pix] = sqrtf(a2 / m0W2);
    }
}

__device__ __forceinline__ float tseqA(int i) {
    if (i == 24) return 0.3f;
    return (float)((double)i * ((0.3 - 0.06)/24.0) + 0.06);
}
__device__ __forceinline__ float tseqB(int i) {
    if (i == 26) return 0.4f;
    return (float)((double)i * ((0.4 - 0.14)/26.0) + 0.14);
}

__device__ __forceinline__ void merge3(float& m0, float& m1, float& m2,
                                       float b0, float b1, float b2) {
    float r0, r1, r2;
    if (m0 <= b0) {
        r0 = m0;
        if (m1 <= b0) { r1 = m1; r2 = fminf(m2, b0); }
        else          { r1 = b0; r2 = fminf(m1, b1); }
    } else {
        r0 = b0;
        if (b1 <= m0) { r1 = b1; r2 = fminf(b2, m0); }
        else          { r1 = m0; r2 = fminf(m1, b1); }
    }
    m0 = r0; m1 = r1; m2 = r2;
}

__device__ __forceinline__ void ins3(float& m0, float& m1, float& m2, float v) {
    if (v < m0)      { m2 = m1; m1 = m0; m0 = v; }
    else if (v < m1) { m2 = m1; m1 = v; }
    else if (v < m2) { m2 = v; }
}

// ---------- 14-row half-image conv inside the fused kernel ----------
// inp: padded [30][30] LDS image; h: [16][30][36] LDS (halos zero); outL: [784] LDS
__device__ void conv14(const float* __restrict__ inp,
                       const float* __restrict__ kA, const float* __restrict__ kB,
                       const float* __restrict__ cbA, float cbB0,
                       float* __restrict__ h, float* __restrict__ outL, int r0)
{
    const int tid = threadIdx.x;
    {
        float4* h4 = (float4*)h;
        for (int i = tid; i < 17280/4; i += 1024) h4[i] = make_float4(0.f,0.f,0.f,0.f);
    }
    __syncthreads();

    // convA: 896 threads = (c, xx); 15 valid h rows, rolling window over padded input
    if (tid < 896) {
        const int c = tid & 31, xx = tid >> 5;
        const float ka0 = kA[0*32+c], ka1 = kA[1*32+c], ka2 = kA[2*32+c];
        const float ka3 = kA[3*32+c], ka4 = kA[4*32+c], ka5 = kA[5*32+c];
        const float ka6 = kA[6*32+c], ka7 = kA[7*32+c], ka8 = kA[8*32+c];
        const float bias = cbA[c];
        const int y0 = (r0 == 0) ? 0 : r0 - 1;       // first valid output-row of h
        float w00 = inp[y0*30+xx],     w01 = inp[y0*30+xx+1],     w02 = inp[y0*30+xx+2];
        float w10 = inp[(y0+1)*30+xx], w11 = inp[(y0+1)*30+xx+1], w12 = inp[(y0+1)*30+xx+2];
        float w20 = inp[(y0+2)*30+xx], w21 = inp[(y0+2)*30+xx+1], w22 = inp[(y0+2)*30+xx+2];
        #pragma unroll
        for (int s = 0; s < 15; ++s) {
            const int y = y0 + s;                    // y in [y0, y0+14], all < 28
            float a = bias;
            a = fmaf(w00, ka0, a); a = fmaf(w01, ka1, a); a = fmaf(w02, ka2, a);
            a = fmaf(w10, ka3, a); a = fmaf(w11, ka4, a); a = fmaf(w12, ka5, a);
            a = fmaf(w20, ka6, a); a = fmaf(w21, ka7, a); a = fmaf(w22, ka8, a);
            const int lr = y - (r0 - 1);             // h row in [0,16)
            h[(lr*30 + xx + 1)*36 + c] = fmaxf(a, 0.f);
            if (s < 14) {
                w00 = w10; w01 = w11; w02 = w12;
                w10 = w20; w11 = w21; w12 = w22;
                const int py = y0 + s + 3;
                w20 = inp[py*30+xx]; w21 = inp[py*30+xx+1]; w22 = inp[py*30+xx+2];
            }
        }
    }
    __syncthreads();

    // convB: 14 rows x 28 outputs x 4 parts = 1568 tasks
    for (int t = tid; t < 1568; t += 1024) {
        const int part = t & 3, o = t >> 2;
        const int xx = o % 28, ly = o / 28;
        const int y = r0 + ly;
        float a = 0.f;
        #pragma unroll
        for (int dy = 0; dy < 3; ++dy) {
            #pragma unroll
            for (int dx = 0; dx < 3; ++dx) {
                const float4* hb = (const float4*)&h[((ly+dy)*30 + xx+dx)*36 + part*8];
                const float4* kb = (const float4*)&kB[(dy*3+dx)*32 + part*8];
                const float4 h0 = hb[0], h1 = hb[1];
                const float4 k0 = kb[0], k1 = kb[1];
                a += h0.x*k0.x; a += h0.y*k0.y; a += h0.z*k0.z; a += h0.w*k0.w;
                a += h1.x*k1.x; a += h1.y*k1.y; a += h1.z*k1.z; a += h1.w*k1.w;
            }
        }
        a += __shfl_xor(a, 1, 64);
        a += __shfl_xor(a, 2, 64);
        if (part == 0) outL[y*GRID + xx] = fmaxf(a + cbB0, 0.f);
    }
    __syncthreads();
}

// ---------- K2': one block per image — conv3 + conv4 + tail, all in LDS ----------
__global__ __launch_bounds__(1024) void fused_kernel(
        const float* __restrict__ k31, const float* __restrict__ cb31,
        const float* __restrict__ k32, const float* __restrict__ cb32,
        const float* __restrict__ k41, const float* __restrict__ cb41,
        const float* __restrict__ k42, const float* __restrict__ cb42,
        const float* __restrict__ W33, const float* __restrict__ b33,
        const float* __restrict__ W43, const float* __restrict__ b43,
        const float* __restrict__ W5,  const float* __restrict__ b5,
        const float* __restrict__ W6,  const float* __restrict__ b6,
        const float* __restrict__ W7,  const float* __restrict__ b7,
        const float* __restrict__ W8,  const float* __restrict__ b8,
        const float* __restrict__ ws,  float* __restrict__ out)
{
    __shared__ float smem[23808];        // 95.2 KB
    float* h    = smem;                  // 17280: [16][30][36]
    float* xc   = smem + 17280;          // 848
    float* in1p = smem + 18128;          // 900: padded [30][30] x2_1
    float* in2p = smem + 19028;          // 900: padded x2_2
    float* x3o  = smem + 19928;          // 784
    float* x4o  = smem + 20712;          // 784
    float* kw   = smem + 21496;          // 1152: k31|k32|k41|k42
    float* cba  = smem + 22648;          // 64:   cb31|cb41
    float* cbb2 = smem + 22712;          // 2:    cb32[0]|cb42[0]
    float* part = smem + 22714;          // 1024
    float* h7f  = smem + 23738;          // 64

    const int b = blockIdx.x, tid = threadIdx.x;
    const int w = tid >> 6, lane = tid & 63;
    const float* x2_1 = ws;
    const float* x2_2 = ws + 12544;
    const float* x1o  = ws + 25088;

    // ---- stage: xc (conv1 out), padded dtm images, conv weights ----
    // (all ranges within the 1024 threads; R7 bug was tid<1218 branches)
    if (tid < NP) xc[tid] = x1o[b*NP + tid];
    if (tid < 900) {
        const int r = tid / 30, c = tid % 30;
        const bool in_ = (r >= 1 && r <= 28 && c >= 1 && c <= 28);
        const int gi = b*NP + (r-1)*GRID + (c-1);
        in1p[tid] = in_ ? x2_1[gi] : 0.f;
        in2p[tid] = in_ ? x2_2[gi] : 0.f;
    }
    for (int i = tid; i < 1152; i += 1024) {
        kw[i] = (i < 288) ? k31[i] : (i < 576) ? k32[i-288]
              : (i < 864) ? k41[i-576] : k42[i-864];
    }
    if (tid < 64) cba[tid] = (tid < 32) ? cb31[tid] : cb41[tid-32];
    if (tid < 2)  cbb2[tid] = (tid == 0) ? cb32[0] : cb42[0];
    __syncthreads();

    // ---- conv3 + conv4, two 14-row halves each ----
    conv14(in1p, kw,       kw+288, cba,      cbb2[0], h, x3o, 0);
    conv14(in1p, kw,       kw+288, cba,      cbb2[0], h, x3o, 14);
    conv14(in2p, kw+576,   kw+864, cba+32,   cbb2[1], h, x4o, 0);
    conv14(in2p, kw+576,   kw+864, cba+32,   cbb2[1], h, x4o, 14);
    // (conv14 ends with __syncthreads: x3o/x4o visible)

    // ---- tail: waves 0-3 wave-local min3+topo; all waves W7 partials ----
    float acc = 0.f;                     // W7 partial, i ascending in [53w, 53w+53)
    const float* Wp = W7 + lane;
    const int i0 = w * 53;

    if (w < 4) {
        // min3 over array w (multiset-invariant repartition)
        const float* srcG = (w == 2) ? (x2_1 + b*NP) : (x2_2 + b*NP);
        const float* srcL = (w == 0) ? x3o : x4o;
        float m0 = INFINITY, m1 = INFINITY, m2 = INFINITY;
        #pragma unroll
        for (int k = 0; k < 13; ++k) {
            const int i = k*64 + lane;
            float v = INFINITY;
            if (i < NP) v = (w < 2) ? srcL[i] : srcG[i];
            ins3(m0, m1, m2, v);
        }
        for (int mask = 1; mask <= 32; mask <<= 1) {
            const float b0 = __shfl_xor(m0, mask, 64);
            const float b1 = __shfl_xor(m1, mask, 64);
            const float b2 = __shfl_xor(m2, mask, 64);
            merge3(m0, m1, m2, b0, b1, b2);
        }
        const float f0 = m0, f1 = m1, f2 = m2;

        // topo matvec (weights from global, constant-trip unrolled)
        const int g = lane >> 4, j = lane & 15;
        float at = 0.f;
        if (w == 0 || w == 2) {               // A: 50 terms
            const float* Wm = (w == 0) ? W33 : W5;
            #pragma unroll
            for (int r = 0; r < 13; ++r) {
                const int i = g + 4*r;
                if (i < 50) {
                    const int t = i >> 1, k = i & 1;
                    const float ts = tseqA(t);
                    const float fk = k ? f1 : f0;
                    const float lam = fmaxf(fminf(ts - fk, 0.3f - ts), 0.f);
                    at = fmaf(lam, Wm[i*16 + j], at);
                }
            }
        } else {                              // B: 81 terms
            const float* Wm = (w == 1) ? W43 : W6;
            #pragma unroll
            for (int r = 0; r < 21; ++r) {
                const int i = g + 4*r;
                if (i < 81) {
                    const int t = i / 3, k = i - t*3;
                    const float ts = tseqB(t);
                    const float fk = (k == 0) ? f0 : (k == 1 ? f1 : f2);
                    const float lam = fmaxf(fminf(ts - fk, 0.4f - ts), 0.f);
                    at = fmaf(lam, Wm[i*16 + j], at);
                }
            }
        }
        at += __shfl_xor(at, 16, 64);
        at += __shfl_xor(at, 32, 64);
        if (lane < 16) {
            const float* bv = (w == 0) ? b33 : (w == 1) ? b43 : (w == 2) ? b5 : b6;
            xc[784 + w*16 + lane] = fmaxf(at + bv[lane], 0.f);
        }
    }

    // W7 partial, part A (i < 784): concurrent with topo waves
    #pragma unroll
    for (int r = 0; r < 53; ++r) {
        const int i = i0 + r;
        if (i < NP) acc = fmaf(xc[i], Wp[i*64], acc);
    }
    __syncthreads();                     // topo region of xc now written

    // W7 partial, part B (i >= 784): same ascending chain continues
    #pragma unroll
    for (int r = 0; r < 53; ++r) {
        const int i = i0 + r;
        if (i >= NP) acc = fmaf(xc[i], Wp[i*64], acc);
    }
    part[w*64 + lane] = acc;
    __syncthreads();

    if (tid < 64) {
        float s = b7[tid];
        #pragma unroll
        for (int k = 0; k < 16; ++k) s += part[k*64 + tid];
        h7f[tid] = fmaxf(s, 0.f);
    }
    __syncthreads();

    if (w < 10) {
        float a2 = h7f[lane] * W8[lane*10 + w];
        for (int m = 32; m; m >>= 1) a2 += __shfl_down(a2, m, 64);
        if (lane == 0) out[b*10 + w] = a2 + b8[w];
    }
}

extern "C" void kernel_launch(void* const* d_in, const int* in_sizes, int n_in,
                              void* d_out, int out_size, void* d_ws, size_t ws_size,
                              hipStream_t stream)
{
    const float* x    = (const float*)d_in[0];
    const float* k11  = (const float*)d_in[1];
    const float* cb11 = (const float*)d_in[2];
    const float* k12  = (const float*)d_in[3];
    const float* cb12 = (const float*)d_in[4];
    const float* k31  = (const float*)d_in[5];
    const float* cb31 = (const float*)d_in[6];
    const float* k32  = (const float*)d_in[7];
    const float* cb32 = (const float*)d_in[8];
    const float* k41  = (const float*)d_in[9];
    const float* cb41 = (const float*)d_in[10];
    const float* k42  = (const float*)d_in[11];
    const float* cb42 = (const float*)d_in[12];
    const float* W33  = (const float*)d_in[13];
    const float* b33  = (const float*)d_in[14];
    const float* W43  = (const float*)d_in[15];
    const float* b43  = (const float*)d_in[16];
    const float* W5   = (const float*)d_in[17];
    const float* b5   = (const float*)d_in[18];
    const float* W6   = (const float*)d_in[19];
    const float* b6   = (const float*)d_in[20];
    const float* W7   = (const float*)d_in[21];
    const float* b7   = (const float*)d_in[22];
    const float* W8   = (const float*)d_in[23];
    const float* b8   = (const float*)d_in[24];
    float* ws  = (float*)d_ws;
    float* out = (float*)d_out;

    k1_kernel   <<<dim3(896), dim3(1024), 0, stream>>>(x, k11, cb11, k12, cb12, ws);
    fused_kernel<<<dim3(16),  dim3(1024), 0, stream>>>(k31, cb31, k32, cb32,
                                                       k41, cb41, k42, cb42,
                                                       W33, b33, W43, b43, W5, b5,
                                                       W6, b6, W7, b7, W8, b8, ws, out);
}

// Round 9
// 30.198 us; speedup vs baseline: 5.4516x; 1.9204x over previous
//
#include <hip/hip_runtime.h>
#include <math.h>

#define GRID 28
#define NP 784

// ---------- compile-time shell-sorted pair table ----------
struct PairTab { unsigned int pk[NP]; float d2[NP]; };
constexpr PairTab make_pairs() {
    PairTab t{};
    int cnt[1459] = {};
    for (int di = 0; di < GRID; ++di)
        for (int dj = 0; dj < GRID; ++dj) cnt[di*di + dj*dj]++;
    int off[1459] = {};
    int acc = 0;
    for (int s = 0; s < 1459; ++s) { off[s] = acc; acc += cnt[s]; }
    const double BY2 = (1.0/13.5) * (1.0/13.5);
    for (int di = 0; di < GRID; ++di)
        for (int dj = 0; dj < GRID; ++dj) {
            int s = di*di + dj*dj;
            int o = off[s]++;
            t.pk[o] = (unsigned)((di << 8) | dj);
            t.d2[o] = (float)((double)s * BY2);
        }
    return t;
}
__constant__ PairTab d_PT = make_pairs();

__device__ __forceinline__ void merge3(float& m0, float& m1, float& m2,
                                       float b0, float b1, float b2) {
    float r0, r1, r2;
    if (m0 <= b0) {
        r0 = m0;
        if (m1 <= b0) { r1 = m1; r2 = fminf(m2, b0); }
        else          { r1 = b0; r2 = fminf(m1, b1); }
    } else {
        r0 = b0;
        if (b1 <= m0) { r1 = b1; r2 = fminf(b2, m0); }
        else          { r1 = m0; r2 = fminf(m1, b1); }
    }
    m0 = r0; m1 = r1; m2 = r2;
}

__device__ __forceinline__ void ins3(float& m0, float& m1, float& m2, float v) {
    if (v < m0)      { m2 = m1; m1 = m0; m0 = v; }
    else if (v < m1) { m2 = m1; m1 = v; }
    else if (v < m2) { m2 = v; }
}

// ---------- conv band path: 4 output rows per block, register-rolling ----------
// smem floats: inl 240 | kAl 288 | kBl 288 | cbl 32 | h 6480 | outSm 112 = 7440
#define CB_SMEM 7440
__device__ void conv_band(const float* __restrict__ in,
                          const float* __restrict__ kA, const float* __restrict__ cbA,
                          const float* __restrict__ kB, const float* __restrict__ cbB,
                          float* __restrict__ outImg, int r0, float* smem,
                          float* __restrict__ minTrip)   // per-band min3 out (or null)
{
    float* inl   = smem;            // 240
    float* kAl   = inl + 240;       // 288
    float* kBl   = kAl + 288;       // 288
    float* cbl   = kBl + 288;       // 32
    float* h     = cbl + 32;        // 6480
    float* outSm = h + 6480;        // 112
    const int tid = threadIdx.x;
    const float cbB0 = cbB[0];

    if (tid < 288)      { kAl[tid] = kA[tid]; kBl[tid] = kB[tid]; }
    else if (tid < 320) cbl[tid - 288] = cbA[tid - 288];
    else if (tid < 560) {
        const int i = tid - 320;
        const int lr = i / 30, col = i % 30;
        const int y = r0 - 2 + lr, ix = col - 1;
        inl[i] = ((unsigned)y < GRID && (unsigned)ix < GRID) ? in[y*GRID + ix] : 0.f;
    }
    {
        float4* h4 = (float4*)h;
        for (int i = tid; i < 6480/4; i += 1024) h4[i] = make_float4(0.f,0.f,0.f,0.f);
    }
    __syncthreads();

    if (tid < 896) {
        const int c = tid & 31, xx = tid >> 5;
        float ka0 = kAl[0*32+c], ka1 = kAl[1*32+c], ka2 = kAl[2*32+c];
        float ka3 = kAl[3*32+c], ka4 = kAl[4*32+c], ka5 = kAl[5*32+c];
        float ka6 = kAl[6*32+c], ka7 = kAl[7*32+c], ka8 = kAl[8*32+c];
        const float bias = cbl[c];
        float w00 = inl[0*30+xx], w01 = inl[0*30+xx+1], w02 = inl[0*30+xx+2];
        float w10 = inl[1*30+xx], w11 = inl[1*30+xx+1], w12 = inl[1*30+xx+2];
        float w20 = inl[2*30+xx], w21 = inl[2*30+xx+1], w22 = inl[2*30+xx+2];
        #pragma unroll
        for (int s = 0; s < 6; ++s) {
            const int y = r0 - 1 + s;
            float a = bias;
            a = fmaf(w00, ka0, a); a = fmaf(w01, ka1, a); a = fmaf(w02, ka2, a);
            a = fmaf(w10, ka3, a); a = fmaf(w11, ka4, a); a = fmaf(w12, ka5, a);
            a = fmaf(w20, ka6, a); a = fmaf(w21, ka7, a); a = fmaf(w22, ka8, a);
            if ((unsigned)y < GRID) h[(s*30 + xx + 1)*36 + c] = fmaxf(a, 0.f);
            if (s < 5) {
                w00 = w10; w01 = w11; w02 = w12;
                w10 = w20; w11 = w21; w12 = w22;
                w20 = inl[(s+3)*30+xx]; w21 = inl[(s+3)*30+xx+1]; w22 = inl[(s+3)*30+xx+2];
            }
        }
    }
    __syncthreads();

    if (tid < 448) {
        const int part = tid & 3, o = tid >> 2;
        const int xx = o % 28, ly = o / 28;
        const int y = r0 + ly;
        float a = 0.f;
        #pragma unroll
        for (int dy = 0; dy < 3; ++dy) {
            #pragma unroll
            for (int dx = 0; dx < 3; ++dx) {
                const float4* hb = (const float4*)&h[((ly+dy)*30 + xx+dx)*36 + part*8];
                const float4* kb = (const float4*)&kBl[(dy*3+dx)*32 + part*8];
                const float4 h0 = hb[0], h1 = hb[1];
                const float4 k0 = kb[0], k1 = kb[1];
                a += h0.x*k0.x; a += h0.y*k0.y; a += h0.z*k0.z; a += h0.w*k0.w;
                a += h1.x*k1.x; a += h1.y*k1.y; a += h1.z*k1.z; a += h1.w*k1.w;
            }
        }
        a += __shfl_xor(a, 1, 64);
        a += __shfl_xor(a, 2, 64);
        if (part == 0) {
            const float v = fmaxf(a + cbB0, 0.f);
            outImg[y*GRID + xx] = v;
            if (minTrip) outSm[o] = v;
        }
    }

    // per-band min3 over the 112 outputs (multiset-invariant partial)
    if (minTrip) {
        __syncthreads();
        if (tid < 64) {
            float m0 = INFINITY, m1 = INFINITY, m2 = INFINITY;
            ins3(m0, m1, m2, outSm[tid]);
            if (tid < 48) ins3(m0, m1, m2, outSm[64 + tid]);
            for (int mask = 1; mask <= 32; mask <<= 1) {
                const float b0 = __shfl_xor(m0, mask, 64);
                const float b1 = __shfl_xor(m1, mask, 64);
                const float b2 = __shfl_xor(m2, mask, 64);
                merge3(m0, m1, m2, b0, b1, b2);
            }
            if (tid == 0) { minTrip[0] = m0; minTrip[1] = m1; minTrip[2] = m2; }
        }
    }
}

// ---------- K1: conv1 (112 blocks) + dtm (784 blocks) ----------
__global__ __launch_bounds__(1024, 8) void k1_kernel(const float* __restrict__ x,
        const float* __restrict__ k11, const float* __restrict__ cb11,
        const float* __restrict__ k12, const float* __restrict__ cb12,
        float* __restrict__ ws)
{
    __shared__ float smem[CB_SMEM];
    const int blk = blockIdx.x;
    const int tid = threadIdx.x;

    if (blk < 112) {                      // conv1: x -> x1o (no min3 needed)
        const int img = blk / 7, band = blk % 7;
        conv_band(x + img*NP, k11, cb11, k12, cb12, ws + 25088 + img*NP, band*4, smem,
                  (float*)0);
        return;
    }

    // ---- dtm ----
    float* wimg = smem;
    float* red  = smem + 784;
    float* out1 = ws;
    float* out2 = ws + 12544;
    const int dblk = blk - 112;
    const int img = dblk / 49, grp = dblk % 49;
    const int w = tid >> 6, lane = tid & 63;

    float v = 0.f;
    if (tid < NP) { v = x[img*NP + tid]; wimg[tid] = v; }
    for (int off = 32; off; off >>= 1) v += __shfl_down(v, off, 64);
    if (lane == 0) red[w] = v;
    __syncthreads();
    float sumw = 0.f;
    #pragma unroll
    for (int i = 0; i < 16; ++i) sumw += red[i];

    const int pix = grp*16 + w;
    const int pr = pix / GRID, pc = pix % GRID;
    const float m0W1 = 0.05f * sumw;
    const float m0W2 = 0.2f  * sumw;
    float a1 = 0.f, a2 = 0.f, carry = 0.f;

    for (int k0 = 0; k0 < NP; k0 += 64) {
        const int idx = k0 + lane;
        const int ii  = idx < NP ? idx : NP-1;
        const unsigned p = d_PT.pk[ii];
        const float dd   = d_PT.d2[ii];
        const int di = (int)(p >> 8);
        const int dj = (int)(p & 255u);
        const int dG = di * GRID;
        const bool rpOK = (pr + di) < GRID;
        const bool rmOK = pr >= di;
        const bool cpOK = (pc + dj) < GRID;
        const bool cmOK = pc >= dj;
        float Wg = 0.f;
        if (rpOK && cpOK)               Wg += wimg[pix + dG + dj];
        if (dj && rpOK && cmOK)         Wg += wimg[pix + dG - dj];
        if (di && rmOK && cpOK)         Wg += wimg[pix - dG + dj];
        if (di && dj && rmOK && cmOK)   Wg += wimg[pix - dG - dj];
        if (idx >= NP) Wg = 0.f;
        float incl = Wg;
        #pragma unroll
        for (int d = 1; d < 64; d <<= 1) {
            const float t = __shfl_up(incl, d, 64);
            if (lane >= d) incl += t;
        }
        const float cumb = carry + (incl - Wg);
        const float e1 = fminf(fmaxf(m0W1 - cumb, 0.f), Wg);
        const float e2 = fminf(fmaxf(m0W2 - cumb, 0.f), Wg);
        a1 = fmaf(e1, dd, a1);
        a2 = fmaf(e2, dd, a2);
        carry += __shfl(incl, 63, 64);
        if (carry >= m0W2) break;
    }
    for (int m = 32; m; m >>= 1) { a1 += __shfl_xor(a1, m, 64); a2 += __shfl_xor(a2, m, 64); }
    if (lane == 0) {
        out1[img*NP + pix] = sqrtf(a1 / m0W1);
        out2[img*NP + pix] = sqrtf(a2 / m0W2);
    }
}

__device__ __forceinline__ float tseqA(int i) {
    if (i == 24) return 0.3f;
    return (float)((double)i * ((0.3 - 0.06)/24.0) + 0.06);
}
__device__ __forceinline__ float tseqB(int i) {
    if (i == 26) return 0.4f;
    return (float)((double)i * ((0.4 - 0.14)/26.0) + 0.14);
}

// topo matvec for one wave holding f0,f1,f2 in all lanes; returns per-lane partial
// (g = lane>>4 i-group, j = lane&15). Caller does the 16/32 shfl reduction.
__device__ __forceinline__ float topoA_partial(const float* __restrict__ Wm,
                                               float f0, float f1, int lane) {
    const int g = lane >> 4, j = lane & 15;
    float at = 0.f;
    #pragma unroll
    for (int r = 0; r < 13; ++r) {
        const int i = g + 4*r;
        if (i < 50) {
            const int t = i >> 1, k = i & 1;
            const float ts = tseqA(t);
            const float fk = k ? f1 : f0;
            const float lam = fmaxf(fminf(ts - fk, 0.3f - ts), 0.f);
            at = fmaf(lam, Wm[i*16 + j], at);
        }
    }
    return at;
}
__device__ __forceinline__ float topoB_partial(const float* __restrict__ Wm,
                                               float f0, float f1, float f2, int lane) {
    const int g = lane >> 4, j = lane & 15;
    float at = 0.f;
    #pragma unroll
    for (int r = 0; r < 21; ++r) {
        const int i = g + 4*r;
        if (i < 81) {
            const int t = i / 3, k = i - t*3;
            const float ts = tseqB(t);
            const float fk = (k == 0) ? f0 : (k == 1 ? f1 : f2);
            const float lam = fmaxf(fminf(ts - fk, 0.4f - ts), 0.f);
            at = fmaf(lam, Wm[i*16 + j], at);
        }
    }
    return at;
}

// ---------- K2: conv3/conv4 bands (224) + topo5/topo6 blocks (32) ----------
// ws triple/topo slots: trip3 @62720 [16][7][3], trip4 @63056, topo5 @63392 [16][16], topo6 @63648
__global__ __launch_bounds__(1024, 8) void k2_kernel(
        const float* __restrict__ k31, const float* __restrict__ cb31,
        const float* __restrict__ k32, const float* __restrict__ cb32,
        const float* __restrict__ k41, const float* __restrict__ cb41,
        const float* __restrict__ k42, const float* __restrict__ cb42,
        const float* __restrict__ W5,  const float* __restrict__ b5,
        const float* __restrict__ W6,  const float* __restrict__ b6,
        float* __restrict__ ws)
{
    __shared__ float smem[CB_SMEM];
    const int blk = blockIdx.x;
    const int tid = threadIdx.x;
    const float* x2_1 = ws;
    const float* x2_2 = ws + 12544;
    float* x3c   = ws + 37632;
    float* x4c   = ws + 50176;
    float* trip3 = ws + 62720;
    float* trip4 = ws + 63056;
    float* topo5 = ws + 63392;
    float* topo6 = ws + 63648;

    if (blk < 112) {
        const int img = blk / 7, band = blk % 7;
        conv_band(x2_1 + img*NP, k31, cb31, k32, cb32, x3c + img*NP, band*4, smem,
                  trip3 + (img*7 + band)*3);
    } else if (blk < 224) {
        const int c = blk - 112;
        const int img = c / 7, band = c % 7;
        conv_band(x2_2 + img*NP, k41, cb41, k42, cb42, x4c + img*NP, band*4, smem,
                  trip4 + (img*7 + band)*3);
    } else {
        // topo5/topo6: wave 0 only; min3 partition identical to R5 (k*64+lane)
        if (tid >= 64) return;
        const int idx = blk - 224;
        const int arr = idx >> 4, img = idx & 15;
        const float* src = (arr == 0) ? (x2_1 + img*NP) : (x2_2 + img*NP);
        const int lane = tid;
        float m0 = INFINITY, m1 = INFINITY, m2 = INFINITY;
        #pragma unroll
        for (int k = 0; k < 13; ++k) {
            const int i = k*64 + lane;
            const float v = (i < NP) ? src[i] : INFINITY;
            ins3(m0, m1, m2, v);
        }
        for (int mask = 1; mask <= 32; mask <<= 1) {
            const float b0 = __shfl_xor(m0, mask, 64);
            const float b1 = __shfl_xor(m1, mask, 64);
            const float b2 = __shfl_xor(m2, mask, 64);
            merge3(m0, m1, m2, b0, b1, b2);
        }
        float at = (arr == 0) ? topoA_partial(W5, m0, m1, lane)
                              : topoB_partial(W6, m0, m1, m2, lane);
        at += __shfl_xor(at, 16, 64);
        at += __shfl_xor(at, 32, 64);
        if (lane < 16) {
            const float* bv = (arr == 0) ? b5 : b6;
            float* dst = (arr == 0) ? topo5 : topo6;
            dst[img*16 + lane] = fmaxf(at + bv[lane], 0.f);
        }
    }
}

// ---------- K3: slim tail — triple merges + topo3/4 + MLP ----------
__global__ __launch_bounds__(1024) void tail_kernel(
        const float* __restrict__ W33, const float* __restrict__ b33,
        const float* __restrict__ W43, const float* __restrict__ b43,
        const float* __restrict__ W7,  const float* __restrict__ b7,
        const float* __restrict__ W8,  const float* __restrict__ b8,
        const float* __restrict__ ws,  float* __restrict__ out)
{
    __shared__ float xc[848];
    __shared__ float part[1024];
    __shared__ float h7f[64];
    const int b = blockIdx.x, tid = threadIdx.x;
    const int w = tid >> 6, lane = tid & 63;
    const float* x1o   = ws + 25088;
    const float* trip3 = ws + 62720;
    const float* trip4 = ws + 63056;
    const float* topo5 = ws + 63392;
    const float* topo6 = ws + 63648;

    if (tid < NP) xc[tid] = x1o[b*NP + tid];
    if (w == 2 && lane < 16) xc[816 + lane] = topo5[b*16 + lane];
    if (w == 3 && lane < 16) xc[832 + lane] = topo6[b*16 + lane];

    if (w < 2) {
        // merge 7 per-band triples (band order 0..6 — multiset-invariant, exact)
        const float* tp = ((w == 0) ? trip3 : trip4) + b*21;
        float m0 = tp[0], m1 = tp[1], m2 = tp[2];
        #pragma unroll
        for (int s = 1; s < 7; ++s)
            merge3(m0, m1, m2, tp[s*3], tp[s*3+1], tp[s*3+2]);
        float at = (w == 0) ? topoA_partial(W33, m0, m1, lane)
                            : topoB_partial(W43, m0, m1, m2, lane);
        at += __shfl_xor(at, 16, 64);
        at += __shfl_xor(at, 32, 64);
        if (lane < 16) {
            const float* bv = (w == 0) ? b33 : b43;
            xc[784 + w*16 + lane] = fmaxf(at + bv[lane], 0.f);
        }
    }
    __syncthreads();

    // relu(xc @ W7 + b7): constant-trip unrolled (batched loads), i ascending
    {
        float acc = 0.f;
        const int i0 = w * 53;
        const float* Wp = W7 + i0*64 + lane;
        #pragma unroll
        for (int r = 0; r < 53; ++r)
            acc = fmaf(xc[i0 + r], Wp[r*64], acc);
        part[w*64 + lane] = acc;
    }
    __syncthreads();
    if (tid < 64) {
        float s = b7[tid];
        #pragma unroll
        for (int k = 0; k < 16; ++k) s += part[k*64 + tid];
        h7f[tid] = fmaxf(s, 0.f);
    }
    __syncthreads();

    if (w < 10) {
        float a2 = h7f[lane] * W8[lane*10 + w];
        for (int m = 32; m; m >>= 1) a2 += __shfl_down(a2, m, 64);
        if (lane == 0) out[b*10 + w] = a2 + b8[w];
    }
}

extern "C" void kernel_launch(void* const* d_in, const int* in_sizes, int n_in,
                              void* d_out, int out_size, void* d_ws, size_t ws_size,
                              hipStream_t stream)
{
    const float* x    = (const float*)d_in[0];
    const float* k11  = (const float*)d_in[1];
    const float* cb11 = (const float*)d_in[2];
    const float* k12  = (const float*)d_in[3];
    const float* cb12 = (const float*)d_in[4];
    const float* k31  = (const float*)d_in[5];
    const float* cb31 = (const float*)d_in[6];
    const float* k32  = (const float*)d_in[7];
    const float* cb32 = (const float*)d_in[8];
    const float* k41  = (const float*)d_in[9];
    const float* cb41 = (const float*)d_in[10];
    const float* k42  = (const float*)d_in[11];
    const float* cb42 = (const float*)d_in[12];
    const float* W33  = (const float*)d_in[13];
    const float* b33  = (const float*)d_in[14];
    const float* W43  = (const float*)d_in[15];
    const float* b43  = (const float*)d_in[16];
    const float* W5   = (const float*)d_in[17];
    const float* b5   = (const float*)d_in[18];
    const float* W6   = (const float*)d_in[19];
    const float* b6   = (const float*)d_in[20];
    const float* W7   = (const float*)d_in[21];
    const float* b7   = (const float*)d_in[22];
    const float* W8   = (const float*)d_in[23];
    const float* b8   = (const float*)d_in[24];
    float* ws  = (float*)d_ws;
    float* out = (float*)d_out;

    k1_kernel  <<<dim3(896), dim3(1024), 0, stream>>>(x, k11, cb11, k12, cb12, ws);
    k2_kernel  <<<dim3(256), dim3(1024), 0, stream>>>(k31, cb31, k32, cb32,
                                                      k41, cb41, k42, cb42,
                                                      W5, b5, W6, b6, ws);
    tail_kernel<<<dim3(16),  dim3(1024), 0, stream>>>(W33, b33, W43, b43,
                                                      W7, b7, W8, b8, ws, out);
}